// Round 14
// baseline (158.345 us; speedup 1.0000x reference)
//
#include <hip/hip_runtime.h>
#include <hip/hip_bf16.h>

#define BB 4
#define HH 160
#define WW 160
#define HWD (HH * WW)                   // 25600
#define OUT_ELEMS (BB * 64 * HWD)       // 6,553,600
#define OFF_ELEMS (BB * 18 * HWD)       // 1,843,200
#define EPSBN 1e-5f
#define CHSTRIDE (8 * HWD)              // 8-channel chunk stride
#define NSLOT 256                       // BN partial slots per channel-stat

typedef __attribute__((ext_vector_type(8))) _Float16 f16x8;
typedef __attribute__((ext_vector_type(4))) float f32x4;

__device__ inline unsigned short f16bits(float a) {
  _Float16 h = (_Float16)a;
  unsigned short u;
  __builtin_memcpy(&u, &h, 2);
  return u;
}

// pack two f32 -> 2x f16 (v_cvt_pkrtz_f16_f32), returned as raw u32 bits
__device__ inline unsigned pkrtz(float a, float b) {
  __fp16 __attribute__((ext_vector_type(2))) t =
      __builtin_amdgcn_cvt_pkrtz(a, b);
  unsigned u;
  __builtin_memcpy(&u, &t, 4);
  return u;
}

// load 8 channel values (stride HWD) and convert to packed f16
__device__ inline f16x8 load8cvt(const float* pp) {
  union { f16x8 v; unsigned u[4]; } r;
  r.u[0] = pkrtz(pp[0], pp[HWD]);
  r.u[1] = pkrtz(pp[2 * HWD], pp[3 * HWD]);
  r.u[2] = pkrtz(pp[4 * HWD], pp[5 * HWD]);
  r.u[3] = pkrtz(pp[6 * HWD], pp[7 * HWD]);
  return r.v;
}

// LDS-only barrier: lgkmcnt wait + raw barrier (global prefetches stay live).
__device__ inline void ldsbar() {
  asm volatile("s_waitcnt lgkmcnt(0)" ::: "memory");
  __builtin_amdgcn_s_barrier();
}

// XCD-slab tile mapping: blk%8 = XCD (HW round-robin); each XCD owns 200
// spatially-contiguous tiles (an 80-pixel-row band) so halo re-reads and
// the offconv->dconv handoff stay inside one 4MB L2.
__device__ inline void tile_map(int blk, int& b, int& ty0, int& tx0) {
  int t = (blk & 7) * 200 + (blk >> 3);
  b = t / 400;
  int r = t % 400;
  ty0 = (r / 10) * 4;
  tx0 = (r % 10) * 16;
}

// ---------------------------------------------------------------------------
// prep: prepacked MFMA B-fragments in FP16 (K permuted to kappa = tap*8 + ch
// within each 8-ch chunk, 96-padded; taps 9..11 zero) + zero BN partials.
// ---------------------------------------------------------------------------
__global__ void prep_kernel(const float* __restrict__ cw,
                            const float* __restrict__ ow,
                            unsigned short* __restrict__ Bp,
                            unsigned short* __restrict__ B2p,
                            float* __restrict__ part) {
  int i = blockIdx.x * 256 + threadIdx.x;
  if (i < 32768) part[i] = 0.f;
  if (i < 49152) {                      // dconv weights conv_w[n][c][t], nt 0..3
    int j = i & 7, l = (i >> 3) & 63, rest = i >> 9;
    int ki = rest % 24, nt = rest / 24;
    int kp = ki * 32 + ((l >> 4) << 3) + j;
    int chunk = kp / 96, kq = kp % 96;
    int t = kq >> 3, c = kq & 7;
    int n = nt * 16 + (l & 15);
    float v = (t < 9) ? cw[n * 576 + (chunk * 8 + c) * 9 + t] : 0.f;
    Bp[i] = f16bits(v);
  }
  if (i < 24576) {                      // offconv weights, nt 0..1, n<18
    int j = i & 7, l = (i >> 3) & 63, rest = i >> 9;
    int ki = rest % 24, nt = rest / 24;
    int kp = ki * 32 + ((l >> 4) << 3) + j;
    int chunk = kp / 96, kq = kp % 96;
    int t = kq >> 3, c = kq & 7;
    int n = nt * 16 + (l & 15);
    float v = (t < 9 && n < 18) ? ow[n * 576 + (chunk * 8 + c) * 9 + t] : 0.f;
    B2p[i] = f16bits(v);
  }
}

// ---------------------------------------------------------------------------
// FUSED offconv + dconv, FP16 path, 1 barrier/chunk, 2x2 phase-2 wave split.
// Rounds 9-13 falsified conflicts / VALU / LDS-throughput / barrier-count as
// limiters (each reduced 30-50%, dur flat at 66-71us). Remaining addressable
// consumer: phase-2's 1x4 N-split makes every wave read ALL 12 Af fragments
// per chunk. This round: wave wv = (mg=wv&1, ng=wv>>1) owns m-frags
// {2mg,2mg+1} x n-frags {2ng,2ng+1} -> 6 Af reads per chunk (half), 6 B
// fragments from L2 (double, prefetch-covered), same 12 MFMAs. Phase 1 was
// already 2x2. Interp / staging / Af writes / schedule byte-identical to
// round 13. LDS = 2*3024 + 2*12288 + 4608 = 35232 B.
// ---------------------------------------------------------------------------
__global__ __launch_bounds__(256, 4) void fused_kernel(
    const float* __restrict__ x, const float* __restrict__ d,
    const f16x8* __restrict__ Bp, const f16x8* __restrict__ B2p,
    float* __restrict__ out, float* __restrict__ off_out,
    float* __restrict__ part) {
  int b, ty0, tx0;
  tile_map(blockIdx.x, b, ty0, tx0);
  const int tid = threadIdx.x;
  const int wv = tid >> 6, lane = tid & 63;
  const int lo = lane >> 4, li = lane & 15;
  const int px = li, py = wv;
  const int h = ty0 + py, w = tx0 + px;

  __shared__ __align__(16) _Float16 patch[2][189 * 8];  // dbuf; ph1: 108 px
  __shared__ f16x8 Af[2][768];                          // dbuf
  __shared__ float offs_s[64 * 18];    // per-pixel 9 taps x (dy,dx)

  const f16x8 zero8 = {(_Float16)0, (_Float16)0, (_Float16)0, (_Float16)0,
                       (_Float16)0, (_Float16)0, (_Float16)0, (_Float16)0};

  // ---- phase-2 x-staging: 189 tasks = one 9x21 pixel each (8ch) ----
  int goff2 = 0, laddr2 = 0;
  bool inr2 = tid < 189, ok2 = false;
  {
    int p = tid;
    int r = p / 21, col = p % 21;
    int gy = ty0 - 2 + r, gx = tx0 - 2 + col;
    ok2 = inr2 && gy >= 0 && gy < HH && gx >= 0 && gx < WW;
    goff2 = ((b * 64) * HH + gy) * WW + gx;
    laddr2 = p * 8;                    // 16B-aligned
  }

  // ================= phase 1: offconv =================
  f32x4 acc0{0.f, 0.f, 0.f, 0.f}, acc1{0.f, 0.f, 0.f, 0.f};
  const int ntA = wv >> 1, mh = wv & 1;
  {
    int poff[3];
    bool tre[3];
#pragma unroll
    for (int kk = 0; kk < 3; ++kk) {
      int t = kk * 4 + lo;
      tre[kk] = (t < 9);
      poff[kk] = tre[kk] ? ((py + t / 3) * 18 + px + t % 3) : 0;
    }

    // phase-1 staging: 108 tasks = one 6x18 pixel each (8ch)
    int goff1 = 0, laddr1 = 0;
    bool inr1 = tid < 108, ok1 = false;
    {
      int p = tid;
      int r = p / 18, col = p % 18;
      int gy = ty0 - 1 + r, gx = tx0 - 1 + col;
      ok1 = inr1 && gy >= 0 && gy < HH && gx >= 0 && gx < WW;
      goff1 = ((b * 64) * HH + gy) * WW + gx;
      laddr1 = p * 8;
    }
    f16x8 g1 = zero8;
    if (ok1) g1 = load8cvt(d + goff1);            // chunk 0
    if (inr1) *(f16x8*)&patch[0][laddr1] = g1;
    ldsbar();                                      // patch[0] ready
    if (ok1) g1 = load8cvt(d + goff1 + CHSTRIDE);  // chunk 1

    for (int chunk = 0; chunk < 8; ++chunk) {
      const int cur = chunk & 1, nxt = cur ^ 1;
      f16x8 bw0 = B2p[((ntA * 24 + chunk * 3 + 0) << 6) + lane];
      f16x8 bw1 = B2p[((ntA * 24 + chunk * 3 + 1) << 6) + lane];
      f16x8 bw2 = B2p[((ntA * 24 + chunk * 3 + 2) << 6) + lane];
#pragma unroll
      for (int kk = 0; kk < 3; ++kk) {
        f16x8 av =
            tre[kk] ? *(const f16x8*)(patch[cur] + poff[kk] * 8) : zero8;
        Af[cur][((wv * 3 + kk) << 6) + lane] = av;
      }
      if (chunk < 7 && inr1) *(f16x8*)&patch[nxt][laddr1] = g1;
      ldsbar();                       // Af[cur] + patch[nxt] ready
      if (chunk < 6 && ok1)
        g1 = load8cvt(d + goff1 + (chunk + 2) * CHSTRIDE);
#pragma unroll
      for (int kk = 0; kk < 3; ++kk) {
        f16x8 bw = (kk == 0) ? bw0 : (kk == 1) ? bw1 : bw2;
        acc0 = __builtin_amdgcn_mfma_f32_16x16x32_f16(
            Af[cur][(((mh * 2) * 3 + kk) << 6) + lane], bw, acc0, 0, 0, 0);
        acc1 = __builtin_amdgcn_mfma_f32_16x16x32_f16(
            Af[cur][(((mh * 2 + 1) * 3 + kk) << 6) + lane], bw, acc1, 0, 0, 0);
      }
    }
  }

  // issue the first x chunk now: HBM latency hides under the phase-1
  // epilogue + phase-boundary barrier
  f16x8 gv = zero8;
  if (ok2) gv = load8cvt(x + goff2);

  {  // phase-1 epilogue: clamp, write global off_out + LDS offs_s
    const int n = ntA * 16 + li;
    if (n < 18) {
#pragma unroll
      for (int f = 0; f < 2; ++f) {
        int mf = mh * 2 + f;
        f32x4 a = f ? acc1 : acc0;
        float* po =
            off_out + ((b * 18 + n) * HH + ty0 + mf) * WW + tx0 + lo * 4;
        float4 v;
        v.x = fminf(1.f, fmaxf(-1.f, a[0]));
        v.y = fminf(1.f, fmaxf(-1.f, a[1]));
        v.z = fminf(1.f, fmaxf(-1.f, a[2]));
        v.w = fminf(1.f, fmaxf(-1.f, a[3]));
        *(float4*)po = v;
        int pix = mf * 16 + lo * 4;
        offs_s[(pix + 0) * 18 + n] = v.x;
        offs_s[(pix + 1) * 18 + n] = v.y;
        offs_s[(pix + 2) * 18 + n] = v.z;
        offs_s[(pix + 3) * 18 + n] = v.w;
      }
    }
  }
  // phase-2 chunk-0 patch write folded before the phase-boundary barrier
  if (inr2) *(f16x8*)&patch[0][laddr2] = gv;
  ldsbar();                            // offs_s + patch2[0] ready

  // ================= phase 2: dconv (2x2 wave split) =================
  const int mg = wv & 1, ng = wv >> 1;
  int bs[3];
  float W00[3], W01[3], W10[3], W11[3];
  bool tre[3];
#pragma unroll
  for (int kk = 0; kk < 3; ++kk) {
    int t = kk * 4 + lo;
    tre[kk] = (t < 9);
    if (tre[kk]) {
      float dy = offs_s[(py * 16 + px) * 18 + 2 * t];
      float dx = offs_s[(py * 16 + px) * 18 + 2 * t + 1];
      float pyf = (float)(h - 1 + t / 3) + dy;
      float pxf = (float)(w - 1 + t % 3) + dx;
      float y0 = floorf(pyf), x0 = floorf(pxf);
      float wy = pyf - y0, wx = pxf - x0;
      bs[kk] = ((int)y0 - (ty0 - 2)) * 21 + ((int)x0 - (tx0 - 2));
      W00[kk] = (1.f - wy) * (1.f - wx);
      W01[kk] = (1.f - wy) * wx;
      W10[kk] = wy * (1.f - wx);
      W11[kk] = wy * wx;
    } else {
      bs[kk] = 0;
      W00[kk] = W01[kk] = W10[kk] = W11[kk] = 0.f;
    }
  }

  f32x4 acc[4];   // acc[i*2+j]: m-frag 2mg+i, n-frag 2ng+j
#pragma unroll
  for (int i = 0; i < 4; ++i) acc[i] = f32x4{0.f, 0.f, 0.f, 0.f};

  if (ok2) gv = load8cvt(x + goff2 + CHSTRIDE);   // chunk 1

  for (int chunk = 0; chunk < 8; ++chunk) {
    const int cur = chunk & 1, nxt = cur ^ 1;
    // 6 B-fragments: n-frags 2ng and 2ng+1, kk 0..2 (L2-resident)
    const f16x8* BcA = Bp + (((2 * ng) * 24 + chunk * 3) << 6) + lane;
    const f16x8* BcB = Bp + (((2 * ng + 1) * 24 + chunk * 3) << 6) + lane;
    f16x8 bwA0 = BcA[0], bwA1 = BcA[64], bwA2 = BcA[128];
    f16x8 bwB0 = BcB[0], bwB1 = BcB[64], bwB2 = BcB[128];
#pragma unroll
    for (int kk = 0; kk < 3; ++kk) {
      f16x8 av;
      if (tre[kk]) {
        const _Float16* q = patch[cur] + bs[kk] * 8;
        f16x8 p00 = *(const f16x8*)(q);            // corner (0,0), 8 ch
        f16x8 p01 = *(const f16x8*)(q + 8);        // corner (0,1)
        f16x8 p10 = *(const f16x8*)(q + 168);      // corner (1,0): +21*8
        f16x8 p11 = *(const f16x8*)(q + 176);      // corner (1,1)
        _Float16 w0 = (_Float16)W00[kk], w1 = (_Float16)W01[kk];
        _Float16 w2 = (_Float16)W10[kk], w3 = (_Float16)W11[kk];
        f16x8 w0v = {w0, w0, w0, w0, w0, w0, w0, w0};
        f16x8 w1v = {w1, w1, w1, w1, w1, w1, w1, w1};
        f16x8 w2v = {w2, w2, w2, w2, w2, w2, w2, w2};
        f16x8 w3v = {w3, w3, w3, w3, w3, w3, w3, w3};
        av = p00 * w0v + p01 * w1v + p10 * w2v + p11 * w3v;
      } else {
        av = zero8;
      }
      Af[cur][((wv * 3 + kk) << 6) + lane] = av;
    }
    if (chunk < 7 && inr2) *(f16x8*)&patch[nxt][laddr2] = gv;
    ldsbar();                         // Af[cur] + patch[nxt] ready
    if (chunk < 6 && ok2)
      gv = load8cvt(x + goff2 + (chunk + 2) * CHSTRIDE);
#pragma unroll
    for (int kk = 0; kk < 3; ++kk) {
      f16x8 bwA = (kk == 0) ? bwA0 : (kk == 1) ? bwA1 : bwA2;
      f16x8 bwB = (kk == 0) ? bwB0 : (kk == 1) ? bwB1 : bwB2;
      f16x8 a0 = Af[cur][(((2 * mg) * 3 + kk) << 6) + lane];
      f16x8 a1 = Af[cur][(((2 * mg + 1) * 3 + kk) << 6) + lane];
      acc[0] = __builtin_amdgcn_mfma_f32_16x16x32_f16(a0, bwA, acc[0], 0, 0, 0);
      acc[1] = __builtin_amdgcn_mfma_f32_16x16x32_f16(a0, bwB, acc[1], 0, 0, 0);
      acc[2] = __builtin_amdgcn_mfma_f32_16x16x32_f16(a1, bwA, acc[2], 0, 0, 0);
      acc[3] = __builtin_amdgcn_mfma_f32_16x16x32_f16(a1, bwB, acc[3], 0, 0, 0);
    }
  }
  // epilogue: aligned float4 stores + fused BN partial sums.
  // acc[i*2+j]: channel (2ng+j)*16+li, row ty0+2mg+i, col tx0+lo*4+r.
  float s[2] = {0.f, 0.f}, s2[2] = {0.f, 0.f};
#pragma unroll
  for (int i = 0; i < 2; ++i) {
#pragma unroll
    for (int j = 0; j < 2; ++j) {
      f32x4 a = acc[i * 2 + j];
      int n = (2 * ng + j) * 16 + li;
      float* po =
          out + ((b * 64 + n) * HH + ty0 + 2 * mg + i) * WW + tx0 + lo * 4;
      *(float4*)po = make_float4(a[0], a[1], a[2], a[3]);
#pragma unroll
      for (int r = 0; r < 4; ++r) {
        float v = a[r];
        s[j] += v;
        s2[j] = fmaf(v, v, s2[j]);
      }
    }
  }
  // reduce across the 4 lanes (lo=0..3) holding the same channel
#pragma unroll
  for (int j = 0; j < 2; ++j) {
    s[j] += __shfl_xor(s[j], 16);
    s[j] += __shfl_xor(s[j], 32);
    s2[j] += __shfl_xor(s2[j], 16);
    s2[j] += __shfl_xor(s2[j], 32);
  }
  if (lo == 0) {
    int slot = blockIdx.x & (NSLOT - 1);
#pragma unroll
    for (int j = 0; j < 2; ++j) {
      int n = (2 * ng + j) * 16 + li;
      atomicAdd(&part[n * NSLOT + slot], s[j]);
      atomicAdd(&part[(64 + n) * NSLOT + slot], s2[j]);
    }
  }
}

// ---------------------------------------------------------------------------
// reduce BN partials: block j sums part[j][0..255] (f64) -> sums[j]
// ---------------------------------------------------------------------------
__global__ __launch_bounds__(256) void reduce_kernel(
    const float* __restrict__ part, double* __restrict__ sums) {
  const int j = blockIdx.x;
  __shared__ double sh[256];
  sh[threadIdx.x] = (double)part[j * NSLOT + threadIdx.x];
  __syncthreads();
  for (int t = 128; t > 0; t >>= 1) {
    if (threadIdx.x < t) sh[threadIdx.x] += sh[threadIdx.x + t];
    __syncthreads();
  }
  if (threadIdx.x == 0) sums[j] = sh[0];
}

// ---------------------------------------------------------------------------
// BN apply + ReLU, in place on d_out's conv region (float4 vectorized).
// ---------------------------------------------------------------------------
__global__ __launch_bounds__(256) void bnapply_kernel(
    float* __restrict__ out, const double* __restrict__ sums,
    const float* __restrict__ gamma, const float* __restrict__ beta) {
  const int i = blockIdx.x * 256 + threadIdx.x;
  if (i >= OUT_ELEMS / 4) return;
  const int o = (i / (HWD / 4)) & 63;
  const float n_inv = 1.0f / (float)(BB * HWD);
  float mean = (float)sums[o] * n_inv;
  float var = (float)sums[64 + o] * n_inv - mean * mean;
  float inv = gamma[o] * rsqrtf(var + EPSBN);
  float bt = beta[o];
  float4 v = ((float4*)out)[i];
  v.x = fmaxf(0.f, (v.x - mean) * inv + bt);
  v.y = fmaxf(0.f, (v.y - mean) * inv + bt);
  v.z = fmaxf(0.f, (v.z - mean) * inv + bt);
  v.w = fmaxf(0.f, (v.w - mean) * inv + bt);
  ((float4*)out)[i] = v;
}

extern "C" void kernel_launch(void* const* d_in, const int* in_sizes, int n_in,
                              void* d_out, int out_size, void* d_ws, size_t ws_size,
                              hipStream_t stream) {
  const float* x = (const float*)d_in[0];
  const float* d = (const float*)d_in[1];
  const float* ow = (const float*)d_in[2];
  const float* cw = (const float*)d_in[3];
  const float* gamma = (const float*)d_in[4];
  const float* beta = (const float*)d_in[5];

  float* out = (float*)d_out;
  float* off_out = out + OUT_ELEMS;

  // ws: sums double[128] | Bp ush[49152] | B2p ush[24576] | part f32[32768]
  double* sums = (double*)d_ws;
  unsigned short* Bp = (unsigned short*)((char*)d_ws + 1024);
  unsigned short* B2p = Bp + 49152;
  float* part = (float*)(B2p + 24576);

  prep_kernel<<<192, 256, 0, stream>>>(cw, ow, Bp, B2p, part);

  fused_kernel<<<1600, 256, 0, stream>>>(x, d, (const f16x8*)Bp,
                                         (const f16x8*)B2p, out, off_out,
                                         part);

  reduce_kernel<<<128, 256, 0, stream>>>(part, sums);
  bnapply_kernel<<<(OUT_ELEMS / 4 + 255) / 256, 256, 0, stream>>>(
      out, sums, gamma, beta);
}

// Round 15
// 152.524 us; speedup vs baseline: 1.0382x; 1.0382x over previous
//
#include <hip/hip_runtime.h>
#include <hip/hip_bf16.h>

#define BB 4
#define HH 160
#define WW 160
#define HWD (HH * WW)                   // 25600
#define OUT_ELEMS (BB * 64 * HWD)       // 6,553,600
#define OFF_ELEMS (BB * 18 * HWD)       // 1,843,200
#define EPSBN 1e-5f
#define CHSTRIDE (8 * HWD)              // 8-channel chunk stride
#define NSLOT 256                       // BN partial slots per channel-stat

typedef __attribute__((ext_vector_type(8))) _Float16 f16x8;
typedef __attribute__((ext_vector_type(4))) float f32x4;

__device__ inline unsigned short f16bits(float a) {
  _Float16 h = (_Float16)a;
  unsigned short u;
  __builtin_memcpy(&u, &h, 2);
  return u;
}

// pack two f32 -> 2x f16 (v_cvt_pkrtz_f16_f32), returned as raw u32 bits
__device__ inline unsigned pkrtz(float a, float b) {
  __fp16 __attribute__((ext_vector_type(2))) t =
      __builtin_amdgcn_cvt_pkrtz(a, b);
  unsigned u;
  __builtin_memcpy(&u, &t, 4);
  return u;
}

// load 8 channel values (stride HWD) and convert to packed f16
__device__ inline f16x8 load8cvt(const float* pp) {
  union { f16x8 v; unsigned u[4]; } r;
  r.u[0] = pkrtz(pp[0], pp[HWD]);
  r.u[1] = pkrtz(pp[2 * HWD], pp[3 * HWD]);
  r.u[2] = pkrtz(pp[4 * HWD], pp[5 * HWD]);
  r.u[3] = pkrtz(pp[6 * HWD], pp[7 * HWD]);
  return r.v;
}

// LDS-only barrier: lgkmcnt wait + raw barrier (global prefetches stay live).
__device__ inline void ldsbar() {
  asm volatile("s_waitcnt lgkmcnt(0)" ::: "memory");
  __builtin_amdgcn_s_barrier();
}

// XCD-slab tile mapping: blk%8 = XCD (HW round-robin); each XCD owns 200
// spatially-contiguous tiles (an 80-pixel-row band) so halo re-reads and
// the offconv->dconv handoff stay inside one 4MB L2.
__device__ inline void tile_map(int blk, int& b, int& ty0, int& tx0) {
  int t = (blk & 7) * 200 + (blk >> 3);
  b = t / 400;
  int r = t % 400;
  ty0 = (r / 10) * 4;
  tx0 = (r % 10) * 16;
}

// ---------------------------------------------------------------------------
// prep: prepacked MFMA B-fragments in FP16 (K permuted to kappa = tap*8 + ch
// within each 8-ch chunk, 96-padded; taps 9..11 zero) + zero BN partials.
// ---------------------------------------------------------------------------
__global__ void prep_kernel(const float* __restrict__ cw,
                            const float* __restrict__ ow,
                            unsigned short* __restrict__ Bp,
                            unsigned short* __restrict__ B2p,
                            float* __restrict__ part) {
  int i = blockIdx.x * 256 + threadIdx.x;
  if (i < 32768) part[i] = 0.f;
  if (i < 49152) {                      // dconv weights conv_w[n][c][t], nt 0..3
    int j = i & 7, l = (i >> 3) & 63, rest = i >> 9;
    int ki = rest % 24, nt = rest / 24;
    int kp = ki * 32 + ((l >> 4) << 3) + j;
    int chunk = kp / 96, kq = kp % 96;
    int t = kq >> 3, c = kq & 7;
    int n = nt * 16 + (l & 15);
    float v = (t < 9) ? cw[n * 576 + (chunk * 8 + c) * 9 + t] : 0.f;
    Bp[i] = f16bits(v);
  }
  if (i < 24576) {                      // offconv weights, nt 0..1, n<18
    int j = i & 7, l = (i >> 3) & 63, rest = i >> 9;
    int ki = rest % 24, nt = rest / 24;
    int kp = ki * 32 + ((l >> 4) << 3) + j;
    int chunk = kp / 96, kq = kp % 96;
    int t = kq >> 3, c = kq & 7;
    int n = nt * 16 + (l & 15);
    float v = (t < 9 && n < 18) ? ow[n * 576 + (chunk * 8 + c) * 9 + t] : 0.f;
    B2p[i] = f16bits(v);
  }
}

// ---------------------------------------------------------------------------
// FUSED offconv + dconv, FP16 path, ONE barrier per chunk. (Final: round-13
// verified-best configuration. Rounds 9-14 falsified conflicts / VALU / LDS
// throughput / barrier count / Af fan-in as limiters -- each reduced 30-50%
// with fused dur flat at 66-71us. The kernel sits at a latency-structural
// plateau: no pipe saturated, ~2.5 effective waves/SIMD, per-chunk dependent
// chains dominate. Both patch and Af double-buffered; chunk schedule is
// {interp->Af[cur] write, patch[nxt] write, ldsbar, prefetch chunk+2, MFMA
// from Af[cur]} -- 18 barriers/block, 2-chunk global prefetch distance.
// LDS = 2*3024 + 2*12288 + 4608 = 35232 B. 52 VGPR, no spill.)
// ---------------------------------------------------------------------------
__global__ __launch_bounds__(256, 4) void fused_kernel(
    const float* __restrict__ x, const float* __restrict__ d,
    const f16x8* __restrict__ Bp, const f16x8* __restrict__ B2p,
    float* __restrict__ out, float* __restrict__ off_out,
    float* __restrict__ part) {
  int b, ty0, tx0;
  tile_map(blockIdx.x, b, ty0, tx0);
  const int tid = threadIdx.x;
  const int wv = tid >> 6, lane = tid & 63;
  const int lo = lane >> 4, li = lane & 15;
  const int px = li, py = wv;
  const int h = ty0 + py, w = tx0 + px;

  __shared__ __align__(16) _Float16 patch[2][189 * 8];  // dbuf; ph1: 108 px
  __shared__ f16x8 Af[2][768];                          // dbuf
  __shared__ float offs_s[64 * 18];    // per-pixel 9 taps x (dy,dx)

  const f16x8 zero8 = {(_Float16)0, (_Float16)0, (_Float16)0, (_Float16)0,
                       (_Float16)0, (_Float16)0, (_Float16)0, (_Float16)0};

  // ---- phase-2 x-staging: 189 tasks = one 9x21 pixel each (8ch) ----
  int goff2 = 0, laddr2 = 0;
  bool inr2 = tid < 189, ok2 = false;
  {
    int p = tid;
    int r = p / 21, col = p % 21;
    int gy = ty0 - 2 + r, gx = tx0 - 2 + col;
    ok2 = inr2 && gy >= 0 && gy < HH && gx >= 0 && gx < WW;
    goff2 = ((b * 64) * HH + gy) * WW + gx;
    laddr2 = p * 8;                    // 16B-aligned
  }

  // ================= phase 1: offconv =================
  f32x4 acc0{0.f, 0.f, 0.f, 0.f}, acc1{0.f, 0.f, 0.f, 0.f};
  const int ntA = wv >> 1, mh = wv & 1;
  {
    int poff[3];
    bool tre[3];
#pragma unroll
    for (int kk = 0; kk < 3; ++kk) {
      int t = kk * 4 + lo;
      tre[kk] = (t < 9);
      poff[kk] = tre[kk] ? ((py + t / 3) * 18 + px + t % 3) : 0;
    }

    // phase-1 staging: 108 tasks = one 6x18 pixel each (8ch)
    int goff1 = 0, laddr1 = 0;
    bool inr1 = tid < 108, ok1 = false;
    {
      int p = tid;
      int r = p / 18, col = p % 18;
      int gy = ty0 - 1 + r, gx = tx0 - 1 + col;
      ok1 = inr1 && gy >= 0 && gy < HH && gx >= 0 && gx < WW;
      goff1 = ((b * 64) * HH + gy) * WW + gx;
      laddr1 = p * 8;
    }
    f16x8 g1 = zero8;
    if (ok1) g1 = load8cvt(d + goff1);            // chunk 0
    if (inr1) *(f16x8*)&patch[0][laddr1] = g1;
    ldsbar();                                      // patch[0] ready
    if (ok1) g1 = load8cvt(d + goff1 + CHSTRIDE);  // chunk 1

    for (int chunk = 0; chunk < 8; ++chunk) {
      const int cur = chunk & 1, nxt = cur ^ 1;
      f16x8 bw0 = B2p[((ntA * 24 + chunk * 3 + 0) << 6) + lane];
      f16x8 bw1 = B2p[((ntA * 24 + chunk * 3 + 1) << 6) + lane];
      f16x8 bw2 = B2p[((ntA * 24 + chunk * 3 + 2) << 6) + lane];
#pragma unroll
      for (int kk = 0; kk < 3; ++kk) {
        f16x8 av =
            tre[kk] ? *(const f16x8*)(patch[cur] + poff[kk] * 8) : zero8;
        Af[cur][((wv * 3 + kk) << 6) + lane] = av;
      }
      if (chunk < 7 && inr1) *(f16x8*)&patch[nxt][laddr1] = g1;
      ldsbar();                       // Af[cur] + patch[nxt] ready
      if (chunk < 6 && ok1)
        g1 = load8cvt(d + goff1 + (chunk + 2) * CHSTRIDE);
#pragma unroll
      for (int kk = 0; kk < 3; ++kk) {
        f16x8 bw = (kk == 0) ? bw0 : (kk == 1) ? bw1 : bw2;
        acc0 = __builtin_amdgcn_mfma_f32_16x16x32_f16(
            Af[cur][(((mh * 2) * 3 + kk) << 6) + lane], bw, acc0, 0, 0, 0);
        acc1 = __builtin_amdgcn_mfma_f32_16x16x32_f16(
            Af[cur][(((mh * 2 + 1) * 3 + kk) << 6) + lane], bw, acc1, 0, 0, 0);
      }
    }
  }

  // issue the first x chunk now: HBM latency hides under the phase-1
  // epilogue + phase-boundary barrier
  f16x8 gv = zero8;
  if (ok2) gv = load8cvt(x + goff2);

  {  // phase-1 epilogue: clamp, write global off_out + LDS offs_s
    const int n = ntA * 16 + li;
    if (n < 18) {
#pragma unroll
      for (int f = 0; f < 2; ++f) {
        int mf = mh * 2 + f;
        f32x4 a = f ? acc1 : acc0;
        float* po =
            off_out + ((b * 18 + n) * HH + ty0 + mf) * WW + tx0 + lo * 4;
        float4 v;
        v.x = fminf(1.f, fmaxf(-1.f, a[0]));
        v.y = fminf(1.f, fmaxf(-1.f, a[1]));
        v.z = fminf(1.f, fmaxf(-1.f, a[2]));
        v.w = fminf(1.f, fmaxf(-1.f, a[3]));
        *(float4*)po = v;
        int pix = mf * 16 + lo * 4;
        offs_s[(pix + 0) * 18 + n] = v.x;
        offs_s[(pix + 1) * 18 + n] = v.y;
        offs_s[(pix + 2) * 18 + n] = v.z;
        offs_s[(pix + 3) * 18 + n] = v.w;
      }
    }
  }
  // phase-2 chunk-0 patch write folded before the phase-boundary barrier
  // (phase-1 patch reads all completed before iter-7's ldsbar)
  if (inr2) *(f16x8*)&patch[0][laddr2] = gv;
  ldsbar();                            // offs_s + patch2[0] ready

  // ================= phase 2: dconv =================
  int bs[3];
  float W00[3], W01[3], W10[3], W11[3];
  bool tre[3];
#pragma unroll
  for (int kk = 0; kk < 3; ++kk) {
    int t = kk * 4 + lo;
    tre[kk] = (t < 9);
    if (tre[kk]) {
      float dy = offs_s[(py * 16 + px) * 18 + 2 * t];
      float dx = offs_s[(py * 16 + px) * 18 + 2 * t + 1];
      float pyf = (float)(h - 1 + t / 3) + dy;
      float pxf = (float)(w - 1 + t % 3) + dx;
      float y0 = floorf(pyf), x0 = floorf(pxf);
      float wy = pyf - y0, wx = pxf - x0;
      bs[kk] = ((int)y0 - (ty0 - 2)) * 21 + ((int)x0 - (tx0 - 2));
      W00[kk] = (1.f - wy) * (1.f - wx);
      W01[kk] = (1.f - wy) * wx;
      W10[kk] = wy * (1.f - wx);
      W11[kk] = wy * wx;
    } else {
      bs[kk] = 0;
      W00[kk] = W01[kk] = W10[kk] = W11[kk] = 0.f;
    }
  }

  f32x4 acc[4];
#pragma unroll
  for (int i = 0; i < 4; ++i) acc[i] = f32x4{0.f, 0.f, 0.f, 0.f};
  const int nt = wv;

  if (ok2) gv = load8cvt(x + goff2 + CHSTRIDE);   // chunk 1

  for (int chunk = 0; chunk < 8; ++chunk) {
    const int cur = chunk & 1, nxt = cur ^ 1;
    f16x8 bw0 = Bp[((nt * 24 + chunk * 3 + 0) << 6) + lane];
    f16x8 bw1 = Bp[((nt * 24 + chunk * 3 + 1) << 6) + lane];
    f16x8 bw2 = Bp[((nt * 24 + chunk * 3 + 2) << 6) + lane];
#pragma unroll
    for (int kk = 0; kk < 3; ++kk) {
      f16x8 av;
      if (tre[kk]) {
        const _Float16* q = patch[cur] + bs[kk] * 8;
        f16x8 p00 = *(const f16x8*)(q);            // corner (0,0), 8 ch
        f16x8 p01 = *(const f16x8*)(q + 8);        // corner (0,1)
        f16x8 p10 = *(const f16x8*)(q + 168);      // corner (1,0): +21*8
        f16x8 p11 = *(const f16x8*)(q + 176);      // corner (1,1)
        _Float16 w0 = (_Float16)W00[kk], w1 = (_Float16)W01[kk];
        _Float16 w2 = (_Float16)W10[kk], w3 = (_Float16)W11[kk];
        f16x8 w0v = {w0, w0, w0, w0, w0, w0, w0, w0};
        f16x8 w1v = {w1, w1, w1, w1, w1, w1, w1, w1};
        f16x8 w2v = {w2, w2, w2, w2, w2, w2, w2, w2};
        f16x8 w3v = {w3, w3, w3, w3, w3, w3, w3, w3};
        av = p00 * w0v + p01 * w1v + p10 * w2v + p11 * w3v;
      } else {
        av = zero8;
      }
      Af[cur][((wv * 3 + kk) << 6) + lane] = av;
    }
    if (chunk < 7 && inr2) *(f16x8*)&patch[nxt][laddr2] = gv;
    ldsbar();                         // Af[cur] + patch[nxt] ready
    if (chunk < 6 && ok2)
      gv = load8cvt(x + goff2 + (chunk + 2) * CHSTRIDE);
#pragma unroll
    for (int kk = 0; kk < 3; ++kk) {
      f16x8 bw = (kk == 0) ? bw0 : (kk == 1) ? bw1 : bw2;
#pragma unroll
      for (int mf = 0; mf < 4; ++mf)
        acc[mf] = __builtin_amdgcn_mfma_f32_16x16x32_f16(
            Af[cur][((mf * 3 + kk) << 6) + lane], bw, acc[mf], 0, 0, 0);
    }
  }
  // epilogue: aligned float4 stores + fused BN partial sums
  const int n = nt * 16 + li;
  float s = 0.f, s2 = 0.f;
#pragma unroll
  for (int mf = 0; mf < 4; ++mf) {
    float* po = out + ((b * 64 + n) * HH + ty0 + mf) * WW + tx0 + lo * 4;
    *(float4*)po = make_float4(acc[mf][0], acc[mf][1], acc[mf][2], acc[mf][3]);
#pragma unroll
    for (int r = 0; r < 4; ++r) {
      float v = acc[mf][r];
      s += v;
      s2 = fmaf(v, v, s2);
    }
  }
  // reduce across the 4 lanes (lo=0..3) holding channel n
  s += __shfl_xor(s, 16);  s += __shfl_xor(s, 32);
  s2 += __shfl_xor(s2, 16); s2 += __shfl_xor(s2, 32);
  if (lo == 0) {
    int slot = blockIdx.x & (NSLOT - 1);
    atomicAdd(&part[n * NSLOT + slot], s);
    atomicAdd(&part[(64 + n) * NSLOT + slot], s2);
  }
}

// ---------------------------------------------------------------------------
// reduce BN partials: block j sums part[j][0..255] (f64) -> sums[j]
// ---------------------------------------------------------------------------
__global__ __launch_bounds__(256) void reduce_kernel(
    const float* __restrict__ part, double* __restrict__ sums) {
  const int j = blockIdx.x;
  __shared__ double sh[256];
  sh[threadIdx.x] = (double)part[j * NSLOT + threadIdx.x];
  __syncthreads();
  for (int t = 128; t > 0; t >>= 1) {
    if (threadIdx.x < t) sh[threadIdx.x] += sh[threadIdx.x + t];
    __syncthreads();
  }
  if (threadIdx.x == 0) sums[j] = sh[0];
}

// ---------------------------------------------------------------------------
// BN apply + ReLU, in place on d_out's conv region (float4 vectorized).
// ---------------------------------------------------------------------------
__global__ __launch_bounds__(256) void bnapply_kernel(
    float* __restrict__ out, const double* __restrict__ sums,
    const float* __restrict__ gamma, const float* __restrict__ beta) {
  const int i = blockIdx.x * 256 + threadIdx.x;
  if (i >= OUT_ELEMS / 4) return;
  const int o = (i / (HWD / 4)) & 63;
  const float n_inv = 1.0f / (float)(BB * HWD);
  float mean = (float)sums[o] * n_inv;
  float var = (float)sums[64 + o] * n_inv - mean * mean;
  float inv = gamma[o] * rsqrtf(var + EPSBN);
  float bt = beta[o];
  float4 v = ((float4*)out)[i];
  v.x = fmaxf(0.f, (v.x - mean) * inv + bt);
  v.y = fmaxf(0.f, (v.y - mean) * inv + bt);
  v.z = fmaxf(0.f, (v.z - mean) * inv + bt);
  v.w = fmaxf(0.f, (v.w - mean) * inv + bt);
  ((float4*)out)[i] = v;
}

extern "C" void kernel_launch(void* const* d_in, const int* in_sizes, int n_in,
                              void* d_out, int out_size, void* d_ws, size_t ws_size,
                              hipStream_t stream) {
  const float* x = (const float*)d_in[0];
  const float* d = (const float*)d_in[1];
  const float* ow = (const float*)d_in[2];
  const float* cw = (const float*)d_in[3];
  const float* gamma = (const float*)d_in[4];
  const float* beta = (const float*)d_in[5];

  float* out = (float*)d_out;
  float* off_out = out + OUT_ELEMS;

  // ws: sums double[128] | Bp ush[49152] | B2p ush[24576] | part f32[32768]
  double* sums = (double*)d_ws;
  unsigned short* Bp = (unsigned short*)((char*)d_ws + 1024);
  unsigned short* B2p = Bp + 49152;
  float* part = (float*)(B2p + 24576);

  prep_kernel<<<192, 256, 0, stream>>>(cw, ow, Bp, B2p, part);

  fused_kernel<<<1600, 256, 0, stream>>>(x, d, (const f16x8*)Bp,
                                         (const f16x8*)B2p, out, off_out,
                                         part);

  reduce_kernel<<<128, 256, 0, stream>>>(part, sums);
  bnapply_kernel<<<(OUT_ELEMS / 4 + 255) / 256, 256, 0, stream>>>(
      out, sums, gamma, beta);
}